// Round 7
// baseline (193.945 us; speedup 1.0000x reference)
//
#include <hip/hip_runtime.h>

// SMPL forward: B=512 batches, V=6890 verts, NB=10 shape dims, NJ=24 joints, 9 extra joints.
// Output fp32 (B, V+33, 3).
//
// Round-7 structure:
//   pre_kernel    (408 blocks)  — batch-independent: jtjs partials AND the
//                                 linearized extra-joint operators P0/PL/W.
//   joints_kernel (512 blocks)  — Rodrigues + chain + A; ALSO computes the 27
//                                 extra-joint outputs per batch from P0/PL/W
//                                 (extra = jre@verts pulled through the LBS
//                                 linearity — exact sum reordering).
//   lbs_kernel    (27x128)      — ROUND-0 VERSION VERBATIM (52.9 µs measured).
// extra_kernel is DELETED: it re-read the full 42 MB vert output after lbs.
//
// lbs scoreboard (do not perturb): s_load/VPT1 = 52.9-54.2 µs << LDS-broadcast
// 114 < VPT2-stream 173 < VPT2-pin 178 < vector-flat 203. Any increase in lbs
// per-thread live state causes spill (r2/r4) or pushes A off the scalar path
// (r5). Never set the 2nd __launch_bounds__ arg (spilled twice).

#define BATCH 512
#define NV 6890
#define NBD 10
#define NJ 24
#define NEXTRA 9
#define NOUT (NV + NJ + NEXTRA)   // 6923
#define VBLK ((NV + 255) / 256)   // 27
#define BPB 4                     // batches per block in LBS kernel
#define PCHUNK 8                  // jtjs V-chunks (partial sums)
#define PCLEN ((NV + PCHUNK - 1) / PCHUNK)  // 862
#define EPN 34                    // per-(e,j) operator floats: 3 P0 + 30 PL + 1 W

__constant__ int c_par[NJ] = {-1,0,0,0,1,2,3,4,5,6,7,8,9,9,9,12,13,14,16,17,18,19,20,21};
// kinematic depth of each joint (parent of depth-k joint has depth k-1)
__constant__ int c_dep[NJ] = {0,1,1,1,2,2,2,3,3,3,4,4,4,4,4,5,5,5,6,6,7,7,8,8};

// ---------------------------------------------------------------------------
// Kernel A (fused): batch-independent precompute. grid (PCHUNK+NEXTRA, NJ)
//  = (17, 24) = 408 blocks (fills the 256-CU chip; old 192-block version
//  underfilled), block 256.
// Role 1 (blockIdx.x < PCHUNK): jtjs partials over V-chunk c for joint j:
//   jtjs_part[c][j][0:3]      = sum_{chunk} Jreg[j,v] * v_template[v,k]
//   jtjs_part[c][j][3+k*10+l] = sum_{chunk} Jreg[j,v] * shapedirs[v,k,l]
// Role 2 (blockIdx.x >= PCHUNK): linearized extra-joint operators, e = x-PCHUNK:
//   u_v = jre[e,v] * lbsw[v,j]
//   epre[e][j][0:3]      = sum_v u_v * v_template[v,k]      (P0)
//   epre[e][j][3+k*10+l] = sum_v u_v * shapedirs[v,k,l]     (PL)
//   epre[e][j][33]       = sum_v u_v                        (W)
// ---------------------------------------------------------------------------
__global__ __launch_bounds__(256) void pre_kernel(
    const float* __restrict__ jreg,
    const float* __restrict__ jre,
    const float* __restrict__ lbsw,
    const float* __restrict__ smpl_t,
    const float* __restrict__ smil_t,
    const float* __restrict__ sdirs,
    const float* __restrict__ msc,
    float* __restrict__ jtjs_part,
    float* __restrict__ epre)
{
    const int j = blockIdx.y;
    const float s = msc[0];

    __shared__ float red[4][EPN];
    const int lane = threadIdx.x & 63, wv = threadIdx.x >> 6;

    if (blockIdx.x < PCHUNK) {
        // ----- role 1: jtjs partial over chunk -----
        const int c = blockIdx.x;
        const int vbeg = c * PCLEN;
        const int vend_ = (vbeg + PCLEN < NV) ? vbeg + PCLEN : NV;

        float acc[33];
#pragma unroll
        for (int i = 0; i < 33; ++i) acc[i] = 0.f;

        for (int v = vbeg + threadIdx.x; v < vend_; v += 256) {
            const float w = jreg[j * NV + v];
#pragma unroll
            for (int k = 0; k < 3; ++k) {
                float vt = s * smpl_t[v * 3 + k] + (1.f - s) * smil_t[v * 3 + k];
                acc[k] = fmaf(w, vt, acc[k]);
            }
            const float2* sd2 = (const float2*)(sdirs + (size_t)v * 30);
#pragma unroll
            for (int i = 0; i < 15; ++i) {
                float2 x = sd2[i];
                acc[3 + 2 * i]     = fmaf(w, x.x, acc[3 + 2 * i]);
                acc[3 + 2 * i + 1] = fmaf(w, x.y, acc[3 + 2 * i + 1]);
            }
        }

#pragma unroll
        for (int i = 0; i < 33; ++i) {
            float x = acc[i];
            for (int off = 32; off; off >>= 1) x += __shfl_xor(x, off, 64);
            acc[i] = x;
        }
        if (lane == 0) {
#pragma unroll
            for (int i = 0; i < 33; ++i) red[wv][i] = acc[i];
        }
        __syncthreads();
        if (threadIdx.x < 33) {
            jtjs_part[(c * NJ + j) * 33 + threadIdx.x] =
                red[0][threadIdx.x] + red[1][threadIdx.x]
              + red[2][threadIdx.x] + red[3][threadIdx.x];
        }
    } else {
        // ----- role 2: extra-joint operators for extra-joint e -----
        const int e = blockIdx.x - PCHUNK;

        float acc[EPN];
#pragma unroll
        for (int i = 0; i < EPN; ++i) acc[i] = 0.f;

        for (int v = threadIdx.x; v < NV; v += 256) {
            const float u = jre[e * NV + v] * lbsw[(size_t)v * NJ + j];
            acc[33] += u;
#pragma unroll
            for (int k = 0; k < 3; ++k) {
                float vt = s * smpl_t[v * 3 + k] + (1.f - s) * smil_t[v * 3 + k];
                acc[k] = fmaf(u, vt, acc[k]);
            }
            const float2* sd2 = (const float2*)(sdirs + (size_t)v * 30);
#pragma unroll
            for (int i = 0; i < 15; ++i) {
                float2 x = sd2[i];
                acc[3 + 2 * i]     = fmaf(u, x.x, acc[3 + 2 * i]);
                acc[3 + 2 * i + 1] = fmaf(u, x.y, acc[3 + 2 * i + 1]);
            }
        }

#pragma unroll
        for (int i = 0; i < EPN; ++i) {
            float x = acc[i];
            for (int off = 32; off; off >>= 1) x += __shfl_xor(x, off, 64);
            acc[i] = x;
        }
        if (lane == 0) {
#pragma unroll
            for (int i = 0; i < EPN; ++i) red[wv][i] = acc[i];
        }
        __syncthreads();
        if (threadIdx.x < EPN) {
            epre[(e * NJ + j) * EPN + threadIdx.x] =
                red[0][threadIdx.x] + red[1][threadIdx.x]
              + red[2][threadIdx.x] + red[3][threadIdx.x];
        }
    }
}

// ---------------------------------------------------------------------------
// Kernel B: per-batch joints — Rodrigues, kinematic chain, A matrices, AND
// the 27 extra-joint outputs (linearized through P0/PL/W; exact reordering of
// extra = Jre @ verts). grid BATCH, block 64. Lanes 0..23 own joint j.
// ---------------------------------------------------------------------------
__global__ __launch_bounds__(64) void joints_kernel(
    const float* __restrict__ betas,
    const float* __restrict__ body_pose,
    const float* __restrict__ glob_or,
    const float* __restrict__ transl,
    const float* __restrict__ jtjs_part,
    const float* __restrict__ epre,
    float* __restrict__ wsA,
    float* __restrict__ out)
{
    const int b = blockIdx.x;
    const int j = threadIdx.x;

    __shared__ float sJ[NJ][3];       // J_shaped
    __shared__ float mats[NJ][12];    // [R | rel_t], then reused for corrected A
    __shared__ float chain[NJ][12];
    __shared__ float sbeta[NBD + 1];
    __shared__ float sS[NEXTRA][NJ][3];  // beta0*(P0 + betas·PL)
    __shared__ float sW[NEXTRA][NJ];

    if (threadIdx.x < NBD + 1) sbeta[threadIdx.x] = betas[b * (NBD + 1) + threadIdx.x];
    __syncthreads();

    if (j < NJ) {
        // sum regressor partials for this joint
        float jt[33];
#pragma unroll
        for (int i = 0; i < 33; ++i) jt[i] = 0.f;
        for (int c = 0; c < PCHUNK; ++c) {
#pragma unroll
            for (int i = 0; i < 33; ++i) jt[i] += jtjs_part[(c * NJ + j) * 33 + i];
        }

        const float beta0 = sbeta[0];
        // J_shaped[b,j,k]
#pragma unroll
        for (int k = 0; k < 3; ++k) {
            float a = jt[k];
#pragma unroll
            for (int l = 0; l < NBD; ++l) a = fmaf(sbeta[1 + l], jt[3 + k * 10 + l], a);
            sJ[j][k] = a * beta0;
        }
        // Rodrigues. angle uses rvec+1e-8 per-component; axis uses raw rvec.
        float rx, ry, rz;
        if (j == 0) {
            rx = glob_or[b * 3 + 0]; ry = glob_or[b * 3 + 1]; rz = glob_or[b * 3 + 2];
        } else {
            rx = body_pose[b * 69 + (j - 1) * 3 + 0];
            ry = body_pose[b * 69 + (j - 1) * 3 + 1];
            rz = body_pose[b * 69 + (j - 1) * 3 + 2];
        }
        float ex = rx + 1e-8f, ey = ry + 1e-8f, ez = rz + 1e-8f;
        float ang = sqrtf(ex * ex + ey * ey + ez * ez);
        float inv = 1.f / ang;
        float ax = rx * inv, ay = ry * inv, az = rz * inv;
        float c = cosf(ang), s = sinf(ang), t = 1.f - c;
        // R = I + s*K + (1-c)*K^2
        mats[j][0]  = 1.f + t * (-(ay * ay + az * az));
        mats[j][1]  = -s * az + t * (ax * ay);
        mats[j][2]  =  s * ay + t * (ax * az);
        mats[j][4]  =  s * az + t * (ax * ay);
        mats[j][5]  = 1.f + t * (-(ax * ax + az * az));
        mats[j][6]  = -s * ax + t * (ay * az);
        mats[j][8]  = -s * ay + t * (ax * az);
        mats[j][9]  =  s * ax + t * (ay * az);
        mats[j][10] = 1.f + t * (-(ax * ax + ay * ay));
    }
    __syncthreads();
    if (j < NJ) {
        const int p = c_par[j];
        float t0 = sJ[j][0], t1 = sJ[j][1], t2 = sJ[j][2];
        if (p >= 0) { t0 -= sJ[p][0]; t1 -= sJ[p][1]; t2 -= sJ[p][2]; }
        mats[j][3] = t0; mats[j][7] = t1; mats[j][11] = t2;
    }
    __syncthreads();
    // chain compose, parallel over kinematic depth levels (max depth 8).
    if (j == 0) {
#pragma unroll
        for (int k = 0; k < 12; ++k) chain[0][k] = mats[0][k];
    }
    __syncthreads();
    for (int lev = 1; lev <= 8; ++lev) {
        if (j < NJ && c_dep[j] == lev) {
            const int p = c_par[j];
            float r_[12];
#pragma unroll
            for (int r = 0; r < 3; ++r) {
#pragma unroll
                for (int col = 0; col < 4; ++col) {
                    float acc = (col == 3) ? chain[p][r * 4 + 3] : 0.f;
#pragma unroll
                    for (int q = 0; q < 3; ++q) acc = fmaf(chain[p][r * 4 + q], mats[j][q * 4 + col], acc);
                    r_[r * 4 + col] = acc;
                }
            }
#pragma unroll
            for (int k = 0; k < 12; ++k) chain[j][k] = r_[k];
        }
        __syncthreads();
    }
    if (j < NJ) {
        float A[12];
#pragma unroll
        for (int k = 0; k < 12; ++k) A[k] = chain[j][k];
        const float c0 = A[3], c1 = A[7], c2 = A[11];
        const float j0 = sJ[j][0], j1 = sJ[j][1], j2 = sJ[j][2];
        A[3]  = c0 - (A[0] * j0 + A[1] * j1 + A[2]  * j2);
        A[7]  = c1 - (A[4] * j0 + A[5] * j1 + A[6]  * j2);
        A[11] = c2 - (A[8] * j0 + A[9] * j1 + A[10] * j2);
#pragma unroll
        for (int k = 0; k < 12; ++k) wsA[((size_t)b * NJ + j) * 12 + k] = A[k];
        // stash corrected A for the extra-joint sum (mats no longer needed)
#pragma unroll
        for (int k = 0; k < 12; ++k) mats[j][k] = A[k];
        // posed joints + transl
        const float tx = transl[b * 3 + 0], ty = transl[b * 3 + 1], tz = transl[b * 3 + 2];
        const size_t o = ((size_t)b * NOUT + NV + j) * 3;
        out[o + 0] = c0 + tx; out[o + 1] = c1 + ty; out[o + 2] = c2 + tz;
    }

    // ---- extra joints: per-batch contraction of the linearized operators ----
    // sS[e][j][c] = beta0 * (P0[e,j,c] + sum_l beta_l * PL[e,j,c,l])
    for (int idx = threadIdx.x; idx < NEXTRA * NJ * 3; idx += 64) {
        const int e  = idx / (NJ * 3);
        const int r  = idx - e * NJ * 3;
        const int jj = r / 3;
        const int cc = r - jj * 3;
        const float* ep = epre + (e * NJ + jj) * EPN;
        float a = ep[cc];
#pragma unroll
        for (int l = 0; l < NBD; ++l) a = fmaf(sbeta[1 + l], ep[3 + cc * 10 + l], a);
        sS[e][jj][cc] = a * sbeta[0];
    }
    for (int idx = threadIdx.x; idx < NEXTRA * NJ; idx += 64) {
        const int e  = idx / NJ;
        const int jj = idx - e * NJ;
        sW[e][jj] = epre[(e * NJ + jj) * EPN + 33];
    }
    __syncthreads();   // mats (corrected A) + sS + sW ready
    if (threadIdx.x < 3 * NEXTRA) {
        const int e = threadIdx.x / 3;
        const int k = threadIdx.x - e * 3;
        float acc = 0.f;
#pragma unroll 4
        for (int jj = 0; jj < NJ; ++jj) {
            acc = fmaf(mats[jj][k * 4 + 0], sS[e][jj][0], acc);
            acc = fmaf(mats[jj][k * 4 + 1], sS[e][jj][1], acc);
            acc = fmaf(mats[jj][k * 4 + 2], sS[e][jj][2], acc);
            acc = fmaf(mats[jj][k * 4 + 3], sW[e][jj],    acc);
        }
        out[((size_t)b * NOUT + NV + NJ) * 3 + threadIdx.x] = acc + transl[b * 3 + k];
    }
}

// ---------------------------------------------------------------------------
// Kernel C: LBS skinning — ROUND-0 VERSION VERBATIM (measured 52.9-54.2 µs,
// VGPR 44, VALUBusy 37%). A[b] block-uniform → scalar s_load path. Measured
// alternatives all regressed (see file header). Do not perturb.
// ---------------------------------------------------------------------------
__global__ __launch_bounds__(256) void lbs_kernel(
    const float* __restrict__ betas,
    const float* __restrict__ transl,
    const float* __restrict__ msc,
    const float* __restrict__ smpl_t,
    const float* __restrict__ smil_t,
    const float* __restrict__ sdirs,
    const float* __restrict__ lbsw,
    const float* __restrict__ wsA,
    float* __restrict__ out)
{
    const int v = blockIdx.x * 256 + threadIdx.x;
    const bool valid = v < NV;
    const int vc = valid ? v : NV - 1;
    const int b0 = blockIdx.y * BPB;
    const float s = msc[0];

    // per-vertex, batch-independent data → registers
    float vt[3];
#pragma unroll
    for (int k = 0; k < 3; ++k)
        vt[k] = s * smpl_t[vc * 3 + k] + (1.f - s) * smil_t[vc * 3 + k];

    float sd[30];
    {
        const float2* sd2 = (const float2*)(sdirs + (size_t)vc * 30);
#pragma unroll
        for (int i = 0; i < 15; ++i) { float2 x = sd2[i]; sd[2 * i] = x.x; sd[2 * i + 1] = x.y; }
    }
    float w[NJ];
    {
        const float4* w4 = (const float4*)(lbsw + (size_t)vc * NJ);
#pragma unroll
        for (int i = 0; i < 6; ++i) {
            float4 x = w4[i];
            w[4 * i] = x.x; w[4 * i + 1] = x.y; w[4 * i + 2] = x.z; w[4 * i + 3] = x.w;
        }
    }

#pragma unroll
    for (int bb = 0; bb < BPB; ++bb) {
        const int b = b0 + bb;
        const float* __restrict__ Bb = betas + b * (NBD + 1);   // uniform
        const float* __restrict__ Ab = wsA + (size_t)b * NJ * 12; // uniform

        // v_shaped
        float vs[3];
#pragma unroll
        for (int k = 0; k < 3; ++k) {
            float a = vt[k];
#pragma unroll
            for (int l = 0; l < NBD; ++l) a = fmaf(Bb[1 + l], sd[k * 10 + l], a);
            vs[k] = a * Bb[0];
        }

        // T = sum_j w_j * A_j (3x4), A uniform → scalar operand in v_fmac
        float T[12];
#pragma unroll
        for (int k = 0; k < 12; ++k) T[k] = 0.f;
#pragma unroll 4
        for (int jj = 0; jj < NJ; ++jj) {
            const float ww = w[jj];
#pragma unroll
            for (int k = 0; k < 12; ++k) T[k] = fmaf(ww, Ab[jj * 12 + k], T[k]);
        }

        if (valid) {
            const float tx = transl[b * 3 + 0], ty = transl[b * 3 + 1], tz = transl[b * 3 + 2];
            const size_t o = ((size_t)b * NOUT + v) * 3;
            out[o + 0] = fmaf(T[0], vs[0], fmaf(T[1], vs[1], fmaf(T[2],  vs[2], T[3])))  + tx;
            out[o + 1] = fmaf(T[4], vs[0], fmaf(T[5], vs[1], fmaf(T[6],  vs[2], T[7])))  + ty;
            out[o + 2] = fmaf(T[8], vs[0], fmaf(T[9], vs[1], fmaf(T[10], vs[2], T[11]))) + tz;
        }
    }
}

// ---------------------------------------------------------------------------
extern "C" void kernel_launch(void* const* d_in, const int* in_sizes, int n_in,
                              void* d_out, int out_size, void* d_ws, size_t ws_size,
                              hipStream_t stream) {
    const float* betas     = (const float*)d_in[0];
    const float* body_pose = (const float*)d_in[1];
    const float* glob_or   = (const float*)d_in[2];
    const float* transl    = (const float*)d_in[3];
    const float* msc       = (const float*)d_in[4];
    const float* smpl_t    = (const float*)d_in[5];
    const float* smil_t    = (const float*)d_in[6];
    const float* sdirs     = (const float*)d_in[7];
    const float* jreg      = (const float*)d_in[8];
    const float* lbsw      = (const float*)d_in[9];
    const float* jre       = (const float*)d_in[10];
    // d_in[11] = parents (hard-coded in c_par)

    float* out  = (float*)d_out;
    float* ws   = (float*)d_ws;
    float* wsA       = ws;                               // BATCH*NJ*12 = 147456 floats
    float* jtjs_part = wsA + (size_t)BATCH * NJ * 12;    // PCHUNK*NJ*33 = 6336
    float* epre      = jtjs_part + PCHUNK * NJ * 33;     // NEXTRA*NJ*34 = 7344

    dim3 gA(PCHUNK + NEXTRA, NJ);
    pre_kernel<<<gA, 256, 0, stream>>>(jreg, jre, lbsw, smpl_t, smil_t, sdirs, msc,
                                       jtjs_part, epre);

    joints_kernel<<<BATCH, 64, 0, stream>>>(betas, body_pose, glob_or, transl,
                                            jtjs_part, epre, wsA, out);

    dim3 gC(VBLK, BATCH / BPB);
    lbs_kernel<<<gC, 256, 0, stream>>>(betas, transl, msc, smpl_t, smil_t, sdirs, lbsw, wsA, out);
}

// Round 8
// 177.291 us; speedup vs baseline: 1.0939x; 1.0939x over previous
//
#include <hip/hip_runtime.h>

// SMPL forward: B=512 batches, V=6890 verts, NB=10 shape dims, NJ=24 joints, 9 extra joints.
// Output fp32 (B, V+33, 3).
//
// Round-8 structure:
//   transpose_kernel (27 blocks)  — one-time: vtT[3][V] (s-blend folded),
//                                   sdT[30][V], lbswT[24][V]. Fixes the
//                                   round-7 regression: role-2 pre blocks were
//                                   gather-bound (stride-96/120B loads = ~64
//                                   cache lines per wave-load, 27 iters x 216
//                                   blocks). All pre loads are now coalesced.
//   pre_kernel     (408 blocks)   — jtjs partials + linearized extra operators.
//   joints_kernel  (512 blocks)   — Rodrigues + chain + A + 27 extra outputs.
//   lbs_kernel     (27x128)       — ROUND-0 VERSION VERBATIM (52.9 µs).
// extra_kernel stays deleted (it re-read the 42 MB vert output after lbs).
//
// lbs scoreboard (do not perturb): s_load/VPT1 = 52.9-54.2 µs << LDS-broadcast
// 114 < VPT2-stream 173 < VPT2-pin 178 < vector-flat 203. Any increase in lbs
// per-thread live state causes spill (r2/r4) or pushes A off the scalar path
// (r5). Never set the 2nd __launch_bounds__ arg (spilled twice).

#define BATCH 512
#define NV 6890
#define NBD 10
#define NJ 24
#define NEXTRA 9
#define NOUT (NV + NJ + NEXTRA)   // 6923
#define VBLK ((NV + 255) / 256)   // 27
#define BPB 4                     // batches per block in LBS kernel
#define PCHUNK 8                  // jtjs V-chunks (partial sums)
#define PCLEN ((NV + PCHUNK - 1) / PCHUNK)  // 862
#define EPN 34                    // per-(e,j) operator floats: 3 P0 + 30 PL + 1 W

__constant__ int c_par[NJ] = {-1,0,0,0,1,2,3,4,5,6,7,8,9,9,9,12,13,14,16,17,18,19,20,21};
// kinematic depth of each joint (parent of depth-k joint has depth k-1)
__constant__ int c_dep[NJ] = {0,1,1,1,2,2,2,3,3,3,4,4,4,4,4,5,5,5,6,6,7,7,8,8};

// ---------------------------------------------------------------------------
// Kernel T: one-time operand transpose (all inputs L2-resident, ~1 µs).
// vtT[k][v]  = s*smpl_t[v,k] + (1-s)*smil_t[v,k]   (blend folded in)
// sdT[i][v]  = shapedirs[v][i]   (i = k*10+l flattened, matches sdirs layout)
// lbswT[j][v]= lbs_weights[v][j]
// Per-thread reads are row-contiguous (vectorized); writes column-coalesced.
// ---------------------------------------------------------------------------
__global__ __launch_bounds__(256) void transpose_kernel(
    const float* __restrict__ smpl_t,
    const float* __restrict__ smil_t,
    const float* __restrict__ sdirs,
    const float* __restrict__ lbsw,
    const float* __restrict__ msc,
    float* __restrict__ vtT,
    float* __restrict__ sdT,
    float* __restrict__ lbswT)
{
    const int v = blockIdx.x * 256 + threadIdx.x;
    if (v >= NV) return;
    const float s = msc[0];
#pragma unroll
    for (int k = 0; k < 3; ++k)
        vtT[k * NV + v] = s * smpl_t[v * 3 + k] + (1.f - s) * smil_t[v * 3 + k];
    const float2* sd2 = (const float2*)(sdirs + (size_t)v * 30);
#pragma unroll
    for (int i = 0; i < 15; ++i) {
        float2 x = sd2[i];
        sdT[(2 * i) * NV + v]     = x.x;
        sdT[(2 * i + 1) * NV + v] = x.y;
    }
    const float4* w4 = (const float4*)(lbsw + (size_t)v * NJ);
#pragma unroll
    for (int i = 0; i < 6; ++i) {
        float4 x = w4[i];
        lbswT[(4 * i) * NV + v]     = x.x;
        lbswT[(4 * i + 1) * NV + v] = x.y;
        lbswT[(4 * i + 2) * NV + v] = x.z;
        lbswT[(4 * i + 3) * NV + v] = x.w;
    }
}

// ---------------------------------------------------------------------------
// Kernel A (fused): batch-independent precompute. grid (PCHUNK+NEXTRA, NJ)
//  = (17, 24) = 408 blocks, block 256. All loads coalesced via vtT/sdT/lbswT.
// Role 1 (blockIdx.x < PCHUNK): jtjs partials over V-chunk c for joint j.
// Role 2 (blockIdx.x >= PCHUNK): linearized extra operators, e = x-PCHUNK:
//   u_v = jre[e,v] * lbsw[v,j];  epre[e][j] = {sum u*vt, sum u*sd, sum u}.
// Summation order identical to round 7 (v ascending, stride 256) → bitwise
// same results.
// ---------------------------------------------------------------------------
__global__ __launch_bounds__(256) void pre_kernel(
    const float* __restrict__ jreg,
    const float* __restrict__ jre,
    const float* __restrict__ vtT,
    const float* __restrict__ sdT,
    const float* __restrict__ lbswT,
    float* __restrict__ jtjs_part,
    float* __restrict__ epre)
{
    const int j = blockIdx.y;

    __shared__ float red[4][EPN];
    const int lane = threadIdx.x & 63, wv = threadIdx.x >> 6;

    if (blockIdx.x < PCHUNK) {
        // ----- role 1: jtjs partial over chunk -----
        const int c = blockIdx.x;
        const int vbeg = c * PCLEN;
        const int vend_ = (vbeg + PCLEN < NV) ? vbeg + PCLEN : NV;

        float acc[33];
#pragma unroll
        for (int i = 0; i < 33; ++i) acc[i] = 0.f;

        for (int v = vbeg + threadIdx.x; v < vend_; v += 256) {
            const float w = jreg[j * NV + v];
#pragma unroll
            for (int k = 0; k < 3; ++k) acc[k] = fmaf(w, vtT[k * NV + v], acc[k]);
#pragma unroll
            for (int i = 0; i < 30; ++i) acc[3 + i] = fmaf(w, sdT[i * NV + v], acc[3 + i]);
        }

#pragma unroll
        for (int i = 0; i < 33; ++i) {
            float x = acc[i];
            for (int off = 32; off; off >>= 1) x += __shfl_xor(x, off, 64);
            acc[i] = x;
        }
        if (lane == 0) {
#pragma unroll
            for (int i = 0; i < 33; ++i) red[wv][i] = acc[i];
        }
        __syncthreads();
        if (threadIdx.x < 33) {
            jtjs_part[(c * NJ + j) * 33 + threadIdx.x] =
                red[0][threadIdx.x] + red[1][threadIdx.x]
              + red[2][threadIdx.x] + red[3][threadIdx.x];
        }
    } else {
        // ----- role 2: extra-joint operators for extra-joint e -----
        const int e = blockIdx.x - PCHUNK;

        float acc[EPN];
#pragma unroll
        for (int i = 0; i < EPN; ++i) acc[i] = 0.f;

        for (int v = threadIdx.x; v < NV; v += 256) {
            const float u = jre[e * NV + v] * lbswT[j * NV + v];
            acc[33] += u;
#pragma unroll
            for (int k = 0; k < 3; ++k) acc[k] = fmaf(u, vtT[k * NV + v], acc[k]);
#pragma unroll
            for (int i = 0; i < 30; ++i) acc[3 + i] = fmaf(u, sdT[i * NV + v], acc[3 + i]);
        }

#pragma unroll
        for (int i = 0; i < EPN; ++i) {
            float x = acc[i];
            for (int off = 32; off; off >>= 1) x += __shfl_xor(x, off, 64);
            acc[i] = x;
        }
        if (lane == 0) {
#pragma unroll
            for (int i = 0; i < EPN; ++i) red[wv][i] = acc[i];
        }
        __syncthreads();
        if (threadIdx.x < EPN) {
            epre[(e * NJ + j) * EPN + threadIdx.x] =
                red[0][threadIdx.x] + red[1][threadIdx.x]
              + red[2][threadIdx.x] + red[3][threadIdx.x];
        }
    }
}

// ---------------------------------------------------------------------------
// Kernel B: per-batch joints — Rodrigues, kinematic chain, A matrices, AND
// the 27 extra-joint outputs. grid BATCH, block 64. Lanes 0..23 own joint j.
// v8: sS/sW phase iterates (e,j) PAIRS (216/64 = 4 iters, per-lane CONTIGUOUS
// 34-float epre row) instead of 648 scattered elements (11 iters x 11 gathers).
// ---------------------------------------------------------------------------
__global__ __launch_bounds__(64) void joints_kernel(
    const float* __restrict__ betas,
    const float* __restrict__ body_pose,
    const float* __restrict__ glob_or,
    const float* __restrict__ transl,
    const float* __restrict__ jtjs_part,
    const float* __restrict__ epre,
    float* __restrict__ wsA,
    float* __restrict__ out)
{
    const int b = blockIdx.x;
    const int j = threadIdx.x;

    __shared__ float sJ[NJ][3];       // J_shaped
    __shared__ float mats[NJ][12];    // [R | rel_t], then reused for corrected A
    __shared__ float chain[NJ][12];
    __shared__ float sbeta[NBD + 1];
    __shared__ float sS[NEXTRA][NJ][3];  // beta0*(P0 + betas·PL)
    __shared__ float sW[NEXTRA][NJ];

    if (threadIdx.x < NBD + 1) sbeta[threadIdx.x] = betas[b * (NBD + 1) + threadIdx.x];
    __syncthreads();

    if (j < NJ) {
        // sum regressor partials for this joint
        float jt[33];
#pragma unroll
        for (int i = 0; i < 33; ++i) jt[i] = 0.f;
        for (int c = 0; c < PCHUNK; ++c) {
#pragma unroll
            for (int i = 0; i < 33; ++i) jt[i] += jtjs_part[(c * NJ + j) * 33 + i];
        }

        const float beta0 = sbeta[0];
        // J_shaped[b,j,k]
#pragma unroll
        for (int k = 0; k < 3; ++k) {
            float a = jt[k];
#pragma unroll
            for (int l = 0; l < NBD; ++l) a = fmaf(sbeta[1 + l], jt[3 + k * 10 + l], a);
            sJ[j][k] = a * beta0;
        }
        // Rodrigues. angle uses rvec+1e-8 per-component; axis uses raw rvec.
        float rx, ry, rz;
        if (j == 0) {
            rx = glob_or[b * 3 + 0]; ry = glob_or[b * 3 + 1]; rz = glob_or[b * 3 + 2];
        } else {
            rx = body_pose[b * 69 + (j - 1) * 3 + 0];
            ry = body_pose[b * 69 + (j - 1) * 3 + 1];
            rz = body_pose[b * 69 + (j - 1) * 3 + 2];
        }
        float ex = rx + 1e-8f, ey = ry + 1e-8f, ez = rz + 1e-8f;
        float ang = sqrtf(ex * ex + ey * ey + ez * ez);
        float inv = 1.f / ang;
        float ax = rx * inv, ay = ry * inv, az = rz * inv;
        float c = cosf(ang), s = sinf(ang), t = 1.f - c;
        // R = I + s*K + (1-c)*K^2
        mats[j][0]  = 1.f + t * (-(ay * ay + az * az));
        mats[j][1]  = -s * az + t * (ax * ay);
        mats[j][2]  =  s * ay + t * (ax * az);
        mats[j][4]  =  s * az + t * (ax * ay);
        mats[j][5]  = 1.f + t * (-(ax * ax + az * az));
        mats[j][6]  = -s * ax + t * (ay * az);
        mats[j][8]  = -s * ay + t * (ax * az);
        mats[j][9]  =  s * ax + t * (ay * az);
        mats[j][10] = 1.f + t * (-(ax * ax + ay * ay));
    }
    __syncthreads();
    if (j < NJ) {
        const int p = c_par[j];
        float t0 = sJ[j][0], t1 = sJ[j][1], t2 = sJ[j][2];
        if (p >= 0) { t0 -= sJ[p][0]; t1 -= sJ[p][1]; t2 -= sJ[p][2]; }
        mats[j][3] = t0; mats[j][7] = t1; mats[j][11] = t2;
    }
    __syncthreads();
    // chain compose, parallel over kinematic depth levels (max depth 8).
    if (j == 0) {
#pragma unroll
        for (int k = 0; k < 12; ++k) chain[0][k] = mats[0][k];
    }
    __syncthreads();
    for (int lev = 1; lev <= 8; ++lev) {
        if (j < NJ && c_dep[j] == lev) {
            const int p = c_par[j];
            float r_[12];
#pragma unroll
            for (int r = 0; r < 3; ++r) {
#pragma unroll
                for (int col = 0; col < 4; ++col) {
                    float acc = (col == 3) ? chain[p][r * 4 + 3] : 0.f;
#pragma unroll
                    for (int q = 0; q < 3; ++q) acc = fmaf(chain[p][r * 4 + q], mats[j][q * 4 + col], acc);
                    r_[r * 4 + col] = acc;
                }
            }
#pragma unroll
            for (int k = 0; k < 12; ++k) chain[j][k] = r_[k];
        }
        __syncthreads();
    }
    if (j < NJ) {
        float A[12];
#pragma unroll
        for (int k = 0; k < 12; ++k) A[k] = chain[j][k];
        const float c0 = A[3], c1 = A[7], c2 = A[11];
        const float j0 = sJ[j][0], j1 = sJ[j][1], j2 = sJ[j][2];
        A[3]  = c0 - (A[0] * j0 + A[1] * j1 + A[2]  * j2);
        A[7]  = c1 - (A[4] * j0 + A[5] * j1 + A[6]  * j2);
        A[11] = c2 - (A[8] * j0 + A[9] * j1 + A[10] * j2);
#pragma unroll
        for (int k = 0; k < 12; ++k) wsA[((size_t)b * NJ + j) * 12 + k] = A[k];
        // stash corrected A for the extra-joint sum (mats no longer needed)
#pragma unroll
        for (int k = 0; k < 12; ++k) mats[j][k] = A[k];
        // posed joints + transl
        const float tx = transl[b * 3 + 0], ty = transl[b * 3 + 1], tz = transl[b * 3 + 2];
        const size_t o = ((size_t)b * NOUT + NV + j) * 3;
        out[o + 0] = c0 + tx; out[o + 1] = c1 + ty; out[o + 2] = c2 + tz;
    }

    // ---- extra joints: per-batch contraction of the linearized operators ----
    // one (e,jj) pair per lane per iter; per-lane epre row is contiguous.
    for (int p = threadIdx.x; p < NEXTRA * NJ; p += 64) {
        const int e  = p / NJ;
        const int jj = p - e * NJ;
        const float* ep = epre + p * EPN;
#pragma unroll
        for (int cc = 0; cc < 3; ++cc) {
            float a = ep[cc];
#pragma unroll
            for (int l = 0; l < NBD; ++l) a = fmaf(sbeta[1 + l], ep[3 + cc * 10 + l], a);
            sS[e][jj][cc] = a * sbeta[0];
        }
        sW[e][jj] = ep[33];
    }
    __syncthreads();   // mats (corrected A) + sS + sW ready
    if (threadIdx.x < 3 * NEXTRA) {
        const int e = threadIdx.x / 3;
        const int k = threadIdx.x - e * 3;
        float acc = 0.f;
#pragma unroll 4
        for (int jj = 0; jj < NJ; ++jj) {
            acc = fmaf(mats[jj][k * 4 + 0], sS[e][jj][0], acc);
            acc = fmaf(mats[jj][k * 4 + 1], sS[e][jj][1], acc);
            acc = fmaf(mats[jj][k * 4 + 2], sS[e][jj][2], acc);
            acc = fmaf(mats[jj][k * 4 + 3], sW[e][jj],    acc);
        }
        out[((size_t)b * NOUT + NV + NJ) * 3 + threadIdx.x] = acc + transl[b * 3 + k];
    }
}

// ---------------------------------------------------------------------------
// Kernel C: LBS skinning — ROUND-0 VERSION VERBATIM (measured 52.9-54.2 µs,
// VGPR 44, VALUBusy 37%). A[b] block-uniform → scalar s_load path. Measured
// alternatives all regressed (see file header). Do not perturb.
// ---------------------------------------------------------------------------
__global__ __launch_bounds__(256) void lbs_kernel(
    const float* __restrict__ betas,
    const float* __restrict__ transl,
    const float* __restrict__ msc,
    const float* __restrict__ smpl_t,
    const float* __restrict__ smil_t,
    const float* __restrict__ sdirs,
    const float* __restrict__ lbsw,
    const float* __restrict__ wsA,
    float* __restrict__ out)
{
    const int v = blockIdx.x * 256 + threadIdx.x;
    const bool valid = v < NV;
    const int vc = valid ? v : NV - 1;
    const int b0 = blockIdx.y * BPB;
    const float s = msc[0];

    // per-vertex, batch-independent data → registers
    float vt[3];
#pragma unroll
    for (int k = 0; k < 3; ++k)
        vt[k] = s * smpl_t[vc * 3 + k] + (1.f - s) * smil_t[vc * 3 + k];

    float sd[30];
    {
        const float2* sd2 = (const float2*)(sdirs + (size_t)vc * 30);
#pragma unroll
        for (int i = 0; i < 15; ++i) { float2 x = sd2[i]; sd[2 * i] = x.x; sd[2 * i + 1] = x.y; }
    }
    float w[NJ];
    {
        const float4* w4 = (const float4*)(lbsw + (size_t)vc * NJ);
#pragma unroll
        for (int i = 0; i < 6; ++i) {
            float4 x = w4[i];
            w[4 * i] = x.x; w[4 * i + 1] = x.y; w[4 * i + 2] = x.z; w[4 * i + 3] = x.w;
        }
    }

#pragma unroll
    for (int bb = 0; bb < BPB; ++bb) {
        const int b = b0 + bb;
        const float* __restrict__ Bb = betas + b * (NBD + 1);   // uniform
        const float* __restrict__ Ab = wsA + (size_t)b * NJ * 12; // uniform

        // v_shaped
        float vs[3];
#pragma unroll
        for (int k = 0; k < 3; ++k) {
            float a = vt[k];
#pragma unroll
            for (int l = 0; l < NBD; ++l) a = fmaf(Bb[1 + l], sd[k * 10 + l], a);
            vs[k] = a * Bb[0];
        }

        // T = sum_j w_j * A_j (3x4), A uniform → scalar operand in v_fmac
        float T[12];
#pragma unroll
        for (int k = 0; k < 12; ++k) T[k] = 0.f;
#pragma unroll 4
        for (int jj = 0; jj < NJ; ++jj) {
            const float ww = w[jj];
#pragma unroll
            for (int k = 0; k < 12; ++k) T[k] = fmaf(ww, Ab[jj * 12 + k], T[k]);
        }

        if (valid) {
            const float tx = transl[b * 3 + 0], ty = transl[b * 3 + 1], tz = transl[b * 3 + 2];
            const size_t o = ((size_t)b * NOUT + v) * 3;
            out[o + 0] = fmaf(T[0], vs[0], fmaf(T[1], vs[1], fmaf(T[2],  vs[2], T[3])))  + tx;
            out[o + 1] = fmaf(T[4], vs[0], fmaf(T[5], vs[1], fmaf(T[6],  vs[2], T[7])))  + ty;
            out[o + 2] = fmaf(T[8], vs[0], fmaf(T[9], vs[1], fmaf(T[10], vs[2], T[11]))) + tz;
        }
    }
}

// ---------------------------------------------------------------------------
extern "C" void kernel_launch(void* const* d_in, const int* in_sizes, int n_in,
                              void* d_out, int out_size, void* d_ws, size_t ws_size,
                              hipStream_t stream) {
    const float* betas     = (const float*)d_in[0];
    const float* body_pose = (const float*)d_in[1];
    const float* glob_or   = (const float*)d_in[2];
    const float* transl    = (const float*)d_in[3];
    const float* msc       = (const float*)d_in[4];
    const float* smpl_t    = (const float*)d_in[5];
    const float* smil_t    = (const float*)d_in[6];
    const float* sdirs     = (const float*)d_in[7];
    const float* jreg      = (const float*)d_in[8];
    const float* lbsw      = (const float*)d_in[9];
    const float* jre       = (const float*)d_in[10];
    // d_in[11] = parents (hard-coded in c_par)

    float* out  = (float*)d_out;
    float* ws   = (float*)d_ws;
    float* wsA       = ws;                               // BATCH*NJ*12 = 147456 floats
    float* jtjs_part = wsA + (size_t)BATCH * NJ * 12;    // PCHUNK*NJ*33 = 6336
    float* epre      = jtjs_part + PCHUNK * NJ * 33;     // NEXTRA*NJ*34 = 7344
    float* vtT       = epre + NEXTRA * NJ * EPN;         // 3*NV  = 20670
    float* sdT       = vtT + 3 * NV;                     // 30*NV = 206700
    float* lbswT     = sdT + 30 * NV;                    // 24*NV = 165360
    // total ws: ~553.9K floats = 2.17 MB

    transpose_kernel<<<VBLK, 256, 0, stream>>>(smpl_t, smil_t, sdirs, lbsw, msc,
                                               vtT, sdT, lbswT);

    dim3 gA(PCHUNK + NEXTRA, NJ);
    pre_kernel<<<gA, 256, 0, stream>>>(jreg, jre, vtT, sdT, lbswT,
                                       jtjs_part, epre);

    joints_kernel<<<BATCH, 64, 0, stream>>>(betas, body_pose, glob_or, transl,
                                            jtjs_part, epre, wsA, out);

    dim3 gC(VBLK, BATCH / BPB);
    lbs_kernel<<<gC, 256, 0, stream>>>(betas, transl, msc, smpl_t, smil_t, sdirs, lbsw, wsA, out);
}

// Round 10
// 174.625 us; speedup vs baseline: 1.1106x; 1.0153x over previous
//
#include <hip/hip_runtime.h>

// SMPL forward: B=512 batches, V=6890 verts, NB=10 shape dims, NJ=24 joints, 9 extra joints.
// Output fp32 (B, V+33, 3).
//
// Round-10 = round-9 resubmission (round-9 bench was an infra flake: container
// failed twice with no compile/pytest signal — same signature as round 1,
// which also ran clean on resubmission).
//
// Structure:
//   transpose_kernel (27 blocks)  — one-time coalesced-operand build.
//   pre_kernel     (408 blocks)   — jtjs partials + linearized extra operators.
//   joints_kernel  (512 blocks)   — Rodrigues + chain + A + 27 extra outputs.
//   lbs_kernel     (27x128)       — round-0 body, + WAVE-STAGGERED batch order.
//
// lbs change rationale: all waves previously hit the A s_load lgkmcnt drain in
// lockstep (same program point, same batch) → co-resident waves could not
// cover each other's stalls → VALUBusy 37%, 53.4 µs vs ~15 µs issue floor.
// Rotating each wave's batch order by (waveId+blockIdx.x)&3 desynchronizes
// the drain points; readfirstlane keeps b wave-uniform → A stays on the
// scalar path. Per-(v,b) math and summation order are UNCHANGED.
//
// Residue floor note: total-minus-lbs has been ~118-144 µs across 3/4/5
// dispatch configurations with only ~10-15 µs of estimated small-kernel
// compute — the rest is per-iteration fixed overhead (launch/drain +
// harness restore dispatches), not addressable by kernel restructuring.
//
// lbs scoreboard (do not perturb structure): s_load/VPT1 = 52.9-54.2 µs <<
// LDS-broadcast 114 < VPT2-stream 173 < VPT2-pin 178 < vector-flat 203.
// Never set the 2nd __launch_bounds__ arg (spilled twice, r2/r4).

#define BATCH 512
#define NV 6890
#define NBD 10
#define NJ 24
#define NEXTRA 9
#define NOUT (NV + NJ + NEXTRA)   // 6923
#define VBLK ((NV + 255) / 256)   // 27
#define BPB 4                     // batches per block in LBS kernel
#define PCHUNK 8                  // jtjs V-chunks (partial sums)
#define PCLEN ((NV + PCHUNK - 1) / PCHUNK)  // 862
#define EPN 34                    // per-(e,j) operator floats: 3 P0 + 30 PL + 1 W

__constant__ int c_par[NJ] = {-1,0,0,0,1,2,3,4,5,6,7,8,9,9,9,12,13,14,16,17,18,19,20,21};
// kinematic depth of each joint (parent of depth-k joint has depth k-1)
__constant__ int c_dep[NJ] = {0,1,1,1,2,2,2,3,3,3,4,4,4,4,4,5,5,5,6,6,7,7,8,8};

// ---------------------------------------------------------------------------
// Kernel T: one-time operand transpose (all inputs L2-resident).
// vtT[k][v]  = s*smpl_t[v,k] + (1-s)*smil_t[v,k]   (blend folded in)
// sdT[i][v]  = shapedirs[v][i]   (i = k*10+l flattened)
// lbswT[j][v]= lbs_weights[v][j]
// ---------------------------------------------------------------------------
__global__ __launch_bounds__(256) void transpose_kernel(
    const float* __restrict__ smpl_t,
    const float* __restrict__ smil_t,
    const float* __restrict__ sdirs,
    const float* __restrict__ lbsw,
    const float* __restrict__ msc,
    float* __restrict__ vtT,
    float* __restrict__ sdT,
    float* __restrict__ lbswT)
{
    const int v = blockIdx.x * 256 + threadIdx.x;
    if (v >= NV) return;
    const float s = msc[0];
#pragma unroll
    for (int k = 0; k < 3; ++k)
        vtT[k * NV + v] = s * smpl_t[v * 3 + k] + (1.f - s) * smil_t[v * 3 + k];
    const float2* sd2 = (const float2*)(sdirs + (size_t)v * 30);
#pragma unroll
    for (int i = 0; i < 15; ++i) {
        float2 x = sd2[i];
        sdT[(2 * i) * NV + v]     = x.x;
        sdT[(2 * i + 1) * NV + v] = x.y;
    }
    const float4* w4 = (const float4*)(lbsw + (size_t)v * NJ);
#pragma unroll
    for (int i = 0; i < 6; ++i) {
        float4 x = w4[i];
        lbswT[(4 * i) * NV + v]     = x.x;
        lbswT[(4 * i + 1) * NV + v] = x.y;
        lbswT[(4 * i + 2) * NV + v] = x.z;
        lbswT[(4 * i + 3) * NV + v] = x.w;
    }
}

// ---------------------------------------------------------------------------
// Kernel A (fused): batch-independent precompute. grid (PCHUNK+NEXTRA, NJ)
//  = (17, 24) = 408 blocks, block 256. All loads coalesced via vtT/sdT/lbswT.
// Role 1 (blockIdx.x < PCHUNK): jtjs partials over V-chunk c for joint j.
// Role 2 (blockIdx.x >= PCHUNK): linearized extra operators, e = x-PCHUNK:
//   u_v = jre[e,v] * lbsw[v,j];  epre[e][j] = {sum u*vt, sum u*sd, sum u}.
// ---------------------------------------------------------------------------
__global__ __launch_bounds__(256) void pre_kernel(
    const float* __restrict__ jreg,
    const float* __restrict__ jre,
    const float* __restrict__ vtT,
    const float* __restrict__ sdT,
    const float* __restrict__ lbswT,
    float* __restrict__ jtjs_part,
    float* __restrict__ epre)
{
    const int j = blockIdx.y;

    __shared__ float red[4][EPN];
    const int lane = threadIdx.x & 63, wv = threadIdx.x >> 6;

    if (blockIdx.x < PCHUNK) {
        // ----- role 1: jtjs partial over chunk -----
        const int c = blockIdx.x;
        const int vbeg = c * PCLEN;
        const int vend_ = (vbeg + PCLEN < NV) ? vbeg + PCLEN : NV;

        float acc[33];
#pragma unroll
        for (int i = 0; i < 33; ++i) acc[i] = 0.f;

        for (int v = vbeg + threadIdx.x; v < vend_; v += 256) {
            const float w = jreg[j * NV + v];
#pragma unroll
            for (int k = 0; k < 3; ++k) acc[k] = fmaf(w, vtT[k * NV + v], acc[k]);
#pragma unroll
            for (int i = 0; i < 30; ++i) acc[3 + i] = fmaf(w, sdT[i * NV + v], acc[3 + i]);
        }

#pragma unroll
        for (int i = 0; i < 33; ++i) {
            float x = acc[i];
            for (int off = 32; off; off >>= 1) x += __shfl_xor(x, off, 64);
            acc[i] = x;
        }
        if (lane == 0) {
#pragma unroll
            for (int i = 0; i < 33; ++i) red[wv][i] = acc[i];
        }
        __syncthreads();
        if (threadIdx.x < 33) {
            jtjs_part[(c * NJ + j) * 33 + threadIdx.x] =
                red[0][threadIdx.x] + red[1][threadIdx.x]
              + red[2][threadIdx.x] + red[3][threadIdx.x];
        }
    } else {
        // ----- role 2: extra-joint operators for extra-joint e -----
        const int e = blockIdx.x - PCHUNK;

        float acc[EPN];
#pragma unroll
        for (int i = 0; i < EPN; ++i) acc[i] = 0.f;

        for (int v = threadIdx.x; v < NV; v += 256) {
            const float u = jre[e * NV + v] * lbswT[j * NV + v];
            acc[33] += u;
#pragma unroll
            for (int k = 0; k < 3; ++k) acc[k] = fmaf(u, vtT[k * NV + v], acc[k]);
#pragma unroll
            for (int i = 0; i < 30; ++i) acc[3 + i] = fmaf(u, sdT[i * NV + v], acc[3 + i]);
        }

#pragma unroll
        for (int i = 0; i < EPN; ++i) {
            float x = acc[i];
            for (int off = 32; off; off >>= 1) x += __shfl_xor(x, off, 64);
            acc[i] = x;
        }
        if (lane == 0) {
#pragma unroll
            for (int i = 0; i < EPN; ++i) red[wv][i] = acc[i];
        }
        __syncthreads();
        if (threadIdx.x < EPN) {
            epre[(e * NJ + j) * EPN + threadIdx.x] =
                red[0][threadIdx.x] + red[1][threadIdx.x]
              + red[2][threadIdx.x] + red[3][threadIdx.x];
        }
    }
}

// ---------------------------------------------------------------------------
// Kernel B: per-batch joints — Rodrigues, kinematic chain, A matrices, AND
// the 27 extra-joint outputs. grid BATCH, block 64. Lanes 0..23 own joint j.
// ---------------------------------------------------------------------------
__global__ __launch_bounds__(64) void joints_kernel(
    const float* __restrict__ betas,
    const float* __restrict__ body_pose,
    const float* __restrict__ glob_or,
    const float* __restrict__ transl,
    const float* __restrict__ jtjs_part,
    const float* __restrict__ epre,
    float* __restrict__ wsA,
    float* __restrict__ out)
{
    const int b = blockIdx.x;
    const int j = threadIdx.x;

    __shared__ float sJ[NJ][3];       // J_shaped
    __shared__ float mats[NJ][12];    // [R | rel_t], then reused for corrected A
    __shared__ float chain[NJ][12];
    __shared__ float sbeta[NBD + 1];
    __shared__ float sS[NEXTRA][NJ][3];  // beta0*(P0 + betas·PL)
    __shared__ float sW[NEXTRA][NJ];

    if (threadIdx.x < NBD + 1) sbeta[threadIdx.x] = betas[b * (NBD + 1) + threadIdx.x];
    __syncthreads();

    if (j < NJ) {
        // sum regressor partials for this joint
        float jt[33];
#pragma unroll
        for (int i = 0; i < 33; ++i) jt[i] = 0.f;
        for (int c = 0; c < PCHUNK; ++c) {
#pragma unroll
            for (int i = 0; i < 33; ++i) jt[i] += jtjs_part[(c * NJ + j) * 33 + i];
        }

        const float beta0 = sbeta[0];
        // J_shaped[b,j,k]
#pragma unroll
        for (int k = 0; k < 3; ++k) {
            float a = jt[k];
#pragma unroll
            for (int l = 0; l < NBD; ++l) a = fmaf(sbeta[1 + l], jt[3 + k * 10 + l], a);
            sJ[j][k] = a * beta0;
        }
        // Rodrigues. angle uses rvec+1e-8 per-component; axis uses raw rvec.
        float rx, ry, rz;
        if (j == 0) {
            rx = glob_or[b * 3 + 0]; ry = glob_or[b * 3 + 1]; rz = glob_or[b * 3 + 2];
        } else {
            rx = body_pose[b * 69 + (j - 1) * 3 + 0];
            ry = body_pose[b * 69 + (j - 1) * 3 + 1];
            rz = body_pose[b * 69 + (j - 1) * 3 + 2];
        }
        float ex = rx + 1e-8f, ey = ry + 1e-8f, ez = rz + 1e-8f;
        float ang = sqrtf(ex * ex + ey * ey + ez * ez);
        float inv = 1.f / ang;
        float ax = rx * inv, ay = ry * inv, az = rz * inv;
        float c = cosf(ang), s = sinf(ang), t = 1.f - c;
        // R = I + s*K + (1-c)*K^2
        mats[j][0]  = 1.f + t * (-(ay * ay + az * az));
        mats[j][1]  = -s * az + t * (ax * ay);
        mats[j][2]  =  s * ay + t * (ax * az);
        mats[j][4]  =  s * az + t * (ax * ay);
        mats[j][5]  = 1.f + t * (-(ax * ax + az * az));
        mats[j][6]  = -s * ax + t * (ay * az);
        mats[j][8]  = -s * ay + t * (ax * az);
        mats[j][9]  =  s * ax + t * (ay * az);
        mats[j][10] = 1.f + t * (-(ax * ax + ay * ay));
    }
    __syncthreads();
    if (j < NJ) {
        const int p = c_par[j];
        float t0 = sJ[j][0], t1 = sJ[j][1], t2 = sJ[j][2];
        if (p >= 0) { t0 -= sJ[p][0]; t1 -= sJ[p][1]; t2 -= sJ[p][2]; }
        mats[j][3] = t0; mats[j][7] = t1; mats[j][11] = t2;
    }
    __syncthreads();
    // chain compose, parallel over kinematic depth levels (max depth 8).
    if (j == 0) {
#pragma unroll
        for (int k = 0; k < 12; ++k) chain[0][k] = mats[0][k];
    }
    __syncthreads();
    for (int lev = 1; lev <= 8; ++lev) {
        if (j < NJ && c_dep[j] == lev) {
            const int p = c_par[j];
            float r_[12];
#pragma unroll
            for (int r = 0; r < 3; ++r) {
#pragma unroll
                for (int col = 0; col < 4; ++col) {
                    float acc = (col == 3) ? chain[p][r * 4 + 3] : 0.f;
#pragma unroll
                    for (int q = 0; q < 3; ++q) acc = fmaf(chain[p][r * 4 + q], mats[j][q * 4 + col], acc);
                    r_[r * 4 + col] = acc;
                }
            }
#pragma unroll
            for (int k = 0; k < 12; ++k) chain[j][k] = r_[k];
        }
        __syncthreads();
    }
    if (j < NJ) {
        float A[12];
#pragma unroll
        for (int k = 0; k < 12; ++k) A[k] = chain[j][k];
        const float c0 = A[3], c1 = A[7], c2 = A[11];
        const float j0 = sJ[j][0], j1 = sJ[j][1], j2 = sJ[j][2];
        A[3]  = c0 - (A[0] * j0 + A[1] * j1 + A[2]  * j2);
        A[7]  = c1 - (A[4] * j0 + A[5] * j1 + A[6]  * j2);
        A[11] = c2 - (A[8] * j0 + A[9] * j1 + A[10] * j2);
#pragma unroll
        for (int k = 0; k < 12; ++k) wsA[((size_t)b * NJ + j) * 12 + k] = A[k];
        // stash corrected A for the extra-joint sum (mats no longer needed)
#pragma unroll
        for (int k = 0; k < 12; ++k) mats[j][k] = A[k];
        // posed joints + transl
        const float tx = transl[b * 3 + 0], ty = transl[b * 3 + 1], tz = transl[b * 3 + 2];
        const size_t o = ((size_t)b * NOUT + NV + j) * 3;
        out[o + 0] = c0 + tx; out[o + 1] = c1 + ty; out[o + 2] = c2 + tz;
    }

    // ---- extra joints: per-batch contraction of the linearized operators ----
    // one (e,jj) pair per lane per iter; per-lane epre row is contiguous.
    for (int p = threadIdx.x; p < NEXTRA * NJ; p += 64) {
        const int e  = p / NJ;
        const int jj = p - e * NJ;
        const float* ep = epre + p * EPN;
#pragma unroll
        for (int cc = 0; cc < 3; ++cc) {
            float a = ep[cc];
#pragma unroll
            for (int l = 0; l < NBD; ++l) a = fmaf(sbeta[1 + l], ep[3 + cc * 10 + l], a);
            sS[e][jj][cc] = a * sbeta[0];
        }
        sW[e][jj] = ep[33];
    }
    __syncthreads();   // mats (corrected A) + sS + sW ready
    if (threadIdx.x < 3 * NEXTRA) {
        const int e = threadIdx.x / 3;
        const int k = threadIdx.x - e * 3;
        float acc = 0.f;
#pragma unroll 4
        for (int jj = 0; jj < NJ; ++jj) {
            acc = fmaf(mats[jj][k * 4 + 0], sS[e][jj][0], acc);
            acc = fmaf(mats[jj][k * 4 + 1], sS[e][jj][1], acc);
            acc = fmaf(mats[jj][k * 4 + 2], sS[e][jj][2], acc);
            acc = fmaf(mats[jj][k * 4 + 3], sW[e][jj],    acc);
        }
        out[((size_t)b * NOUT + NV + NJ) * 3 + threadIdx.x] = acc + transl[b * 3 + k];
    }
}

// ---------------------------------------------------------------------------
// Kernel C: LBS skinning. Round-0 body (VGPR 44, scalar A path) with ONE
// change: the batch loop order is rotated per wave — b visits
// b0 + ((bb + waveId + blockIdx.x) & 3) — so co-resident waves hit their
// A s_load lgkmcnt drains at DIFFERENT times and cover each other's stalls
// (previously lockstep → VALUBusy 37%). readfirstlane keeps the rotation
// wave-uniform → b stays uniform → A stays on the scalar s_load path.
// Per-(v,b) arithmetic and summation order unchanged (bitwise-same output).
// Tripwires: VGPR must stay 44; WRITE_SIZE must stay 41.7 MB.
// ---------------------------------------------------------------------------
__global__ __launch_bounds__(256) void lbs_kernel(
    const float* __restrict__ betas,
    const float* __restrict__ transl,
    const float* __restrict__ msc,
    const float* __restrict__ smpl_t,
    const float* __restrict__ smil_t,
    const float* __restrict__ sdirs,
    const float* __restrict__ lbsw,
    const float* __restrict__ wsA,
    float* __restrict__ out)
{
    // wave-uniform rotation of the batch order (SGPR via readfirstlane),
    // hoisted before all loads
    const int rot = __builtin_amdgcn_readfirstlane((int)(threadIdx.x >> 6) + (int)blockIdx.x);

    const int v = blockIdx.x * 256 + threadIdx.x;
    const bool valid = v < NV;
    const int vc = valid ? v : NV - 1;
    const int b0 = blockIdx.y * BPB;
    const float s = msc[0];

    // per-vertex, batch-independent data → registers
    float vt[3];
#pragma unroll
    for (int k = 0; k < 3; ++k)
        vt[k] = s * smpl_t[vc * 3 + k] + (1.f - s) * smil_t[vc * 3 + k];

    float sd[30];
    {
        const float2* sd2 = (const float2*)(sdirs + (size_t)vc * 30);
#pragma unroll
        for (int i = 0; i < 15; ++i) { float2 x = sd2[i]; sd[2 * i] = x.x; sd[2 * i + 1] = x.y; }
    }
    float w[NJ];
    {
        const float4* w4 = (const float4*)(lbsw + (size_t)vc * NJ);
#pragma unroll
        for (int i = 0; i < 6; ++i) {
            float4 x = w4[i];
            w[4 * i] = x.x; w[4 * i + 1] = x.y; w[4 * i + 2] = x.z; w[4 * i + 3] = x.w;
        }
    }

#pragma unroll
    for (int bb = 0; bb < BPB; ++bb) {
        const int b = b0 + ((bb + rot) & (BPB - 1));
        const float* __restrict__ Bb = betas + b * (NBD + 1);   // uniform
        const float* __restrict__ Ab = wsA + (size_t)b * NJ * 12; // uniform

        // v_shaped
        float vs[3];
#pragma unroll
        for (int k = 0; k < 3; ++k) {
            float a = vt[k];
#pragma unroll
            for (int l = 0; l < NBD; ++l) a = fmaf(Bb[1 + l], sd[k * 10 + l], a);
            vs[k] = a * Bb[0];
        }

        // T = sum_j w_j * A_j (3x4), A uniform → scalar operand in v_fmac
        float T[12];
#pragma unroll
        for (int k = 0; k < 12; ++k) T[k] = 0.f;
#pragma unroll 4
        for (int jj = 0; jj < NJ; ++jj) {
            const float ww = w[jj];
#pragma unroll
            for (int k = 0; k < 12; ++k) T[k] = fmaf(ww, Ab[jj * 12 + k], T[k]);
        }

        if (valid) {
            const float tx = transl[b * 3 + 0], ty = transl[b * 3 + 1], tz = transl[b * 3 + 2];
            const size_t o = ((size_t)b * NOUT + v) * 3;
            out[o + 0] = fmaf(T[0], vs[0], fmaf(T[1], vs[1], fmaf(T[2],  vs[2], T[3])))  + tx;
            out[o + 1] = fmaf(T[4], vs[0], fmaf(T[5], vs[1], fmaf(T[6],  vs[2], T[7])))  + ty;
            out[o + 2] = fmaf(T[8], vs[0], fmaf(T[9], vs[1], fmaf(T[10], vs[2], T[11]))) + tz;
        }
    }
}

// ---------------------------------------------------------------------------
extern "C" void kernel_launch(void* const* d_in, const int* in_sizes, int n_in,
                              void* d_out, int out_size, void* d_ws, size_t ws_size,
                              hipStream_t stream) {
    const float* betas     = (const float*)d_in[0];
    const float* body_pose = (const float*)d_in[1];
    const float* glob_or   = (const float*)d_in[2];
    const float* transl    = (const float*)d_in[3];
    const float* msc       = (const float*)d_in[4];
    const float* smpl_t    = (const float*)d_in[5];
    const float* smil_t    = (const float*)d_in[6];
    const float* sdirs     = (const float*)d_in[7];
    const float* jreg      = (const float*)d_in[8];
    const float* lbsw      = (const float*)d_in[9];
    const float* jre       = (const float*)d_in[10];
    // d_in[11] = parents (hard-coded in c_par)

    float* out  = (float*)d_out;
    float* ws   = (float*)d_ws;
    float* wsA       = ws;                               // BATCH*NJ*12 = 147456 floats
    float* jtjs_part = wsA + (size_t)BATCH * NJ * 12;    // PCHUNK*NJ*33 = 6336
    float* epre      = jtjs_part + PCHUNK * NJ * 33;     // NEXTRA*NJ*34 = 7344
    float* vtT       = epre + NEXTRA * NJ * EPN;         // 3*NV  = 20670
    float* sdT       = vtT + 3 * NV;                     // 30*NV = 206700
    float* lbswT     = sdT + 30 * NV;                    // 24*NV = 165360

    transpose_kernel<<<VBLK, 256, 0, stream>>>(smpl_t, smil_t, sdirs, lbsw, msc,
                                               vtT, sdT, lbswT);

    dim3 gA(PCHUNK + NEXTRA, NJ);
    pre_kernel<<<gA, 256, 0, stream>>>(jreg, jre, vtT, sdT, lbswT,
                                       jtjs_part, epre);

    joints_kernel<<<BATCH, 64, 0, stream>>>(betas, body_pose, glob_or, transl,
                                            jtjs_part, epre, wsA, out);

    dim3 gC(VBLK, BATCH / BPB);
    lbs_kernel<<<gC, 256, 0, stream>>>(betas, transl, msc, smpl_t, smil_t, sdirs, lbsw, wsA, out);
}